// Round 19
// baseline (192.171 us; speedup 1.0000x reference)
//
#include <hip/hip_runtime.h>
#include <math.h>

#define NFFT 512
#define HOP 128
#define NBINS 257
#define ROW 1028          // 4*257
#define CHUNK 64
#define LAM64 0.19783147f // 0.975^64
#define LAM2  0.950625f   // 0.975^2
#define NG1F 512
#define NG1C 128
// LDS swizzle for FFT buffers: bijective, applied to EVERY access.
#define SWZ(a) ((a) ^ (((a) >> 4) & 15))

__device__ __forceinline__ float2 cmul(float2 a, float2 b) {
  return make_float2(a.x * b.x - a.y * b.y, a.x * b.y + a.y * b.x);
}

struct EB { float lg, sv, cv, msp; };

// ---------- prep: twiddle table (once) + sparse filterbank spans ----------
__global__ void k_prep(const float* __restrict__ fb, int* __restrict__ lohi,
                       float2* __restrict__ twg) {
  int t = threadIdx.x;
  for (int i = t; i < NFFT; i += 256) {
    double ang = -6.283185307179586476925286766559 * (double)i / (double)NFFT;
    twg[i] = make_float2((float)cos(ang), (float)sin(ang));
  }
  for (int m = t; m < NBINS; m += 256) {
    int lo = 0, hi = -1;
    for (int f = 0; f < NBINS; ++f) {
      if (fb[f * NBINS + m] != 0.0f) { if (hi < 0) lo = f; hi = f; }
    }
    lohi[m] = lo;
    lohi[NBINS + m] = hi;
  }
}

// ---------- per-bin epilogue (S = swizzled LDS array, off = subarray base) ----------
__device__ __forceinline__ EB epilogue_bin(const float2* __restrict__ S, int off,
                                           float* __restrict__ out, unsigned ob,
                                           int k, bool store) {
  float2 z = S[SWZ(off + k)];
  float mag, sv, cv;
  if (k == 0 || k == 256) {
    // z.y is EXACTLY 0 here. The f32 reference's sin column at these bins is
    // either 0 (re>=0) or the single constant sin(pi_f32) (re<0). After
    // F.normalize the column becomes sign/sqrt(N_neg) — independent of the
    // constant's magnitude — so a cheap sign-select replaces sinf(atan2f()).
    mag = fabsf(z.x);
    sv = (z.x < 0.0f) ? -8.742278e-8f : 0.0f;
    cv = copysignf(1.0f, z.x);
  } else {
    float r2 = fmaf(z.x, z.x, z.y * z.y);
    if (r2 > 0.0f) {
      float rs = __builtin_amdgcn_rsqf(r2);
      mag = r2 * rs;            // sqrt(r2) to ~1ulp
      sv = z.y * rs;            // sin(angle) = im/|z|
      cv = z.x * rs;            // cos(angle) = re/|z|
    } else { mag = 0.0f; sv = 0.0f; cv = 1.0f; }
  }
  float lg = __logf(mag + 1e-9f);
  if (store) {
    out[ob + k] = lg;
    out[ob + 2 * NBINS + k] = sv;
    out[ob + 3 * NBINS + k] = cv;
  }
  // hann spectrum via 3-tap stencil; X[-1] = conj(X[1])
  float2 zm, zp;
  if (k == 0) { float2 s1 = S[SWZ(off + 1)]; zm = make_float2(s1.x, -s1.y); }
  else zm = S[SWZ(off + k - 1)];
  zp = S[SWZ(off + k + 1)];
  float hr = 0.5f * z.x - 0.25f * (zm.x + zp.x);
  float hi = 0.5f * z.y - 0.25f * (zm.y + zp.y);
  EB e; e.lg = lg; e.sv = sv; e.cv = cv; e.msp = hr * hr + hi * hi;
  return e;
}

// ---------- unpack one bin: fused final radix-2 + real/imag split ----------
__device__ __forceinline__ void unpack_bin(const float2* __restrict__ x,
                                           float2* __restrict__ y, int k) {
  float2 Zk, Zm;
  if (k <= 255) {
    float2 a0 = x[SWZ(k)], a1 = x[SWZ(k + 256)];
    Zk = make_float2(a0.x + a1.x, a0.y + a1.y);
  } else {
    float2 a0 = x[SWZ(k - 256)], a1 = x[SWZ(k)];
    Zk = make_float2(a0.x - a1.x, a0.y - a1.y);
  }
  int m2 = (NFFT - k) & (NFFT - 1);
  if (k == 0 || k == 256) {
    Zm = Zk;                       // structural: X1.im = X2.im = 0 exactly
  } else if (m2 >= 256) {          // k in 1..255
    float2 b0 = x[SWZ(m2 - 256)], b1 = x[SWZ(m2)];
    Zm = make_float2(b0.x - b1.x, b0.y - b1.y);
  } else {                         // k == 257 -> m2 = 255
    float2 b0 = x[SWZ(m2)], b1 = x[SWZ(m2 + 256)];
    Zm = make_float2(b0.x + b1.x, b0.y + b1.y);
  }
  y[SWZ(k)] = make_float2(0.5f * (Zk.x + Zm.x), 0.5f * (Zk.y - Zm.y));
  y[SWZ(258 + k)] = make_float2(0.5f * (Zk.y + Zm.y), 0.5f * (Zm.x - Zk.x));
}

// ---------- 2 frames per block (1 complex FFT), 128 threads ----------
// Barrier domain shrunk from 4 waves (2 independent FFTs) to the 2 waves that
// actually exchange data; LDS/block 16.6->8.3KB (16 blocks/CU -> ~full
// occupancy). seg staging is now same-thread (the r18 cross-wave pattern is
// structurally gone). Emits partF (771 sumsq partials) + segB (pcen scan seg).
__global__ __launch_bounds__(128) void k_fft(
    const float* __restrict__ audio, const float* __restrict__ fb,
    const int* __restrict__ lohi, const float2* __restrict__ twg,
    float* __restrict__ out, float* __restrict__ partF,
    float* __restrict__ segB, int T, int nframes) {
  __shared__ float2 bufA[520];
  __shared__ float2 bufB[520];

  const int v = threadIdx.x;   // butterfly index, 0..127
  const int fr0 = blockIdx.x * 2;
  const int fr1 = fr0 + 1;
  const bool h0 = fr0 < nframes;
  const bool h1 = fr1 < nframes;

  // fused load + stage 0: packed frame pair z = frame0 + i*frame1, reflect pad
  int s0 = fr0 * HOP - NFFT / 2;
  float2 xr[4];
#pragma unroll
  for (int j = 0; j < 4; ++j) {
    int i = v + 128 * j;
    int q0 = s0 + i;
    if (q0 < 0) q0 = -q0;
    if (q0 >= T) q0 = 2 * T - 2 - q0;
    int q1 = s0 + HOP + i;
    if (q1 < 0) q1 = -q1;
    if (q1 >= T) q1 = 2 * T - 2 - q1;
    xr[j] = make_float2(audio[q0], h1 ? audio[q1] : 0.0f);
  }
  {
    // stage 0 (m=1, qm=v, o=4v), register-local
    float2 w1 = twg[v], w2 = twg[2 * v], w3 = twg[3 * v];
    float2 s02 = make_float2(xr[0].x + xr[2].x, xr[0].y + xr[2].y);
    float2 d02 = make_float2(xr[0].x - xr[2].x, xr[0].y - xr[2].y);
    float2 s13 = make_float2(xr[1].x + xr[3].x, xr[1].y + xr[3].y);
    float2 d13 = make_float2(xr[1].x - xr[3].x, xr[1].y - xr[3].y);
    int o = 4 * v;
    bufB[SWZ(o)] = make_float2(s02.x + s13.x, s02.y + s13.y);
    bufB[SWZ(o + 1)] = cmul(w1, make_float2(d02.x + d13.y, d02.y - d13.x));  // d02 - i*d13
    bufB[SWZ(o + 2)] = cmul(w2, make_float2(s02.x - s13.x, s02.y - s13.y));
    bufB[SWZ(o + 3)] = cmul(w3, make_float2(d02.x - d13.y, d02.y + d13.x));  // d02 + i*d13
  }
  __syncthreads();

  // stages 1..3: bufB -> bufA -> bufB -> bufA (hoisted swizzled read addrs)
  const int ra0 = SWZ(v), ra1 = SWZ(v + 128), ra2 = SWZ(v + 256), ra3 = SWZ(v + 384);
  float2* x = bufB;
  float2* y = bufA;
#pragma unroll
  for (int ds = 1; ds < 4; ++ds) {
    const int m = 1 << (2 * ds);
    int qm = v & ~(m - 1);
    int r = v - qm;
    int o = 4 * qm + r;
    float2 w1 = twg[qm];
    float2 w2 = twg[2 * qm];
    float2 w3 = twg[3 * qm];
    float2 x0 = x[ra0], x1 = x[ra1], x2 = x[ra2], x3 = x[ra3];
    float2 s02 = make_float2(x0.x + x2.x, x0.y + x2.y);
    float2 d02 = make_float2(x0.x - x2.x, x0.y - x2.y);
    float2 s13 = make_float2(x1.x + x3.x, x1.y + x3.y);
    float2 d13 = make_float2(x1.x - x3.x, x1.y - x3.y);
    float2 E0 = make_float2(s02.x + s13.x, s02.y + s13.y);
    float2 u1 = make_float2(d02.x + d13.y, d02.y - d13.x);  // d02 - i*d13
    float2 u2 = make_float2(s02.x - s13.x, s02.y - s13.y);
    float2 u3 = make_float2(d02.x - d13.y, d02.y + d13.x);  // d02 + i*d13
    float2 E1 = cmul(w1, u1);
    float2 E2 = cmul(w2, u2);
    float2 E3 = cmul(w3, u3);
    y[SWZ(o)] = E0;
    y[SWZ(o + m)] = E1;
    y[SWZ(o + 2 * m)] = E2;
    y[SWZ(o + 3 * m)] = E3;
    __syncthreads();
    float2* tmp = x; x = y; y = tmp;
  }
  // After the loop: x == bufA (stage-3 output), y == bufB.
  // Unpack: bins 0..255 in 2 full iterations; 256/257 by lanes v<2.
  unpack_bin(x, y, v);
  unpack_bin(x, y, v + 128);
  if (v < 2) unpack_bin(x, y, 256 + v);
  __syncthreads();

  // epilogue: bins 0..255 in 2 full iterations; bin 256 by lane v==0
  unsigned ob0 = (unsigned)fr0 * ROW;
  unsigned ob1 = (unsigned)fr1 * ROW;
  float mspA[2], mspB[2], sql[2], sqs[2], sqc[2];
#pragma unroll
  for (int ki = 0; ki < 2; ++ki) {
    int k = v + 128 * ki;
    EB e0 = epilogue_bin(y, 0, out, ob0, k, h0);
    EB e1 = epilogue_bin(y, 258, out, ob1, k, h1);
    mspA[ki] = e0.msp;
    mspB[ki] = e1.msp;
    sql[ki] = (h0 ? e0.lg * e0.lg : 0.f) + (h1 ? e1.lg * e1.lg : 0.f);
    sqs[ki] = (h0 ? e0.sv * e0.sv : 0.f) + (h1 ? e1.sv * e1.sv : 0.f);
    sqc[ki] = (h0 ? e0.cv * e0.cv : 0.f) + (h1 ? e1.cv * e1.cv : 0.f);
  }
  float mspA6 = 0.f, mspB6 = 0.f, sql6 = 0.f, sqs6 = 0.f, sqc6 = 0.f;
  if (v == 0) {
    EB e0 = epilogue_bin(y, 0, out, ob0, 256, h0);
    EB e1 = epilogue_bin(y, 258, out, ob1, 256, h1);
    mspA6 = e0.msp;
    mspB6 = e1.msp;
    sql6 = (h0 ? e0.lg * e0.lg : 0.f) + (h1 ? e1.lg * e1.lg : 0.f);
    sqs6 = (h0 ? e0.sv * e0.sv : 0.f) + (h1 ? e1.sv * e1.sv : 0.f);
    sqc6 = (h0 ? e0.cv * e0.cv : 0.f) + (h1 ? e1.cv * e1.cv : 0.f);
  }
  __syncthreads();   // all reads of y (spectra) done -> bufB reusable

  // park: mspec (both frames) in bufB; squares in bufA
  float* mspSh = (float*)&bufB[0];  // [0..257) frame0, [258..515) frame1; [520..777) seg
  float* sqf = (float*)&bufA[0];    // ch0 [0..257), ch2 [258..515), ch3 [516..773)
#pragma unroll
  for (int ki = 0; ki < 2; ++ki) {
    int k = v + 128 * ki;
    mspSh[k] = mspA[ki];
    mspSh[258 + k] = mspB[ki];
    sqf[k] = sql[ki];
    sqf[258 + k] = sqs[ki];
    sqf[516 + k] = sqc[ki];
  }
  if (v == 0) {
    mspSh[256] = mspA6;
    mspSh[258 + 256] = mspB6;
    sqf[256] = sql6;
    sqf[258 + 256] = sqs6;
    sqf[516 + 256] = sqc6;
  }
  __syncthreads();

  // sparse mel for both frames; seg staged at [520+m] — SAME thread writes and
  // later reads each element (m and i ranges coincide), so no barrier needed.
  for (int m = v; m < NBINS; m += 128) {
    int lo = lohi[m], hi = lohi[NBINS + m];
    float a0 = 0.0f, a1 = 0.0f;
    for (int f = lo; f <= hi; ++f) {
      float w = fb[f * NBINS + m];
      a0 = fmaf(mspSh[f], w, a0);
      a1 = fmaf(mspSh[258 + f], w, a1);
    }
    if (h0) out[ob0 + NBINS + m] = a0;
    if (h1) out[ob1 + NBINS + m] = a1;
    mspSh[520 + m] = fmaf(0.975f, a0, a1);   // lam*x_first + x_second
  }

  // partF row (sumsq partials; gaps at 257/515 skipped via lidx) + seg
  for (int i = v; i < 771; i += 128) {
    int lidx = i + (i >= 257) + (i >= 514);
    partF[(unsigned)blockIdx.x * 771u + i] = sqf[lidx];
  }
  for (int i = v; i < NBINS; i += 128) {
    segB[(unsigned)blockIdx.x * 257u + i] = 0.025f * mspSh[520 + i];
  }
}

// ---------- mend from segs: mend[c] = sum_g LAM2^(31-g) seg[32c+g] ----------
__global__ __launch_bounds__(320) void k_mend(const float* __restrict__ segB,
                                              float* __restrict__ mend,
                                              int nfb, int chunks) {
  int m = threadIdx.x;
  if (m >= NBINS) return;
  int c = blockIdx.x;
  float xs[32];
#pragma unroll
  for (int g = 0; g < 32; ++g) {
    int b = 32 * c + g;
    xs[g] = (b < nfb) ? segB[(unsigned)b * 257u + m] : 0.0f;
  }
  float mm = 0.0f;
#pragma unroll
  for (int g = 0; g < 32; ++g) mm = fmaf(LAM2, mm, xs[g]);
  mend[c * NBINS + m] = mm;
}

// ---------- pcen phase C: init from prev 12 chunks' mend (LAM64^12=3.6e-9),
// scan+rewrite ch1; ch1 column-square partials free from registers ----------
__global__ __launch_bounds__(320) void k_pcen_c(float* __restrict__ out,
                                                const float* __restrict__ mend,
                                                float* __restrict__ partC,
                                                int nframes) {
  int m = threadIdx.x;
  if (m >= NBINS) return;
  int c = blockIdx.x;
  int F0 = c * CHUNK;
  int end = min(F0 + CHUNK, nframes);
  const float SS = 0.025f, OMS = 1.0f - SS;
  const float SQ2 = sqrtf(2.0f);
  float mm;
  if (c >= 12) {
    float xs[12];
#pragma unroll
    for (int j = 0; j < 12; ++j) xs[j] = mend[(c - 12 + j) * NBINS + m];
    mm = 0.0f;
#pragma unroll
    for (int j = 0; j < 12; ++j) mm = xs[j] + LAM64 * mm;
  } else {
    mm = 0.0f;
    for (int j = 0; j < c; ++j) mm = mend[j * NBINS + m] + LAM64 * mm;
  }
  float acc1 = 0.0f;
  int tf = F0;
  for (; tf + 16 <= end; tf += 16) {
    float xs[16], ys[16];
#pragma unroll
    for (int j = 0; j < 16; ++j) xs[j] = out[(unsigned)(tf + j) * ROW + NBINS + m];
#pragma unroll
    for (int j = 0; j < 16; ++j) {
      mm = OMS * mm + SS * xs[j];
      float invden = __expf(-0.98f * __logf(mm + 1e-6f));  // 1/den, no division
      float val = fmaf(xs[j], invden, 2.0f);
      float rs = __builtin_amdgcn_rsqf(val);
      ys[j] = val * rs - SQ2;   // sqrt(val) - sqrt(2), ~1ulp
      acc1 = fmaf(ys[j], ys[j], acc1);
    }
#pragma unroll
    for (int j = 0; j < 16; ++j) out[(unsigned)(tf + j) * ROW + NBINS + m] = ys[j];
  }
  for (; tf < end; ++tf) {
    unsigned idx = (unsigned)tf * ROW + NBINS + m;
    float xv = out[idx];
    mm = OMS * mm + SS * xv;
    float invden = __expf(-0.98f * __logf(mm + 1e-6f));
    float val = fmaf(xv, invden, 2.0f);
    float rs = __builtin_amdgcn_rsqf(val);
    float yv = val * rs - SQ2;
    acc1 = fmaf(yv, yv, acc1);
    out[idx] = yv;
  }
  partC[c * NBINS + m] = acc1;
}

// ---------- norm stage 1: coalesced AND parallel (512+128 blocks, 4-row batch) ----------
__global__ __launch_bounds__(256) void k_norm1(const float* __restrict__ partF,
                                               const float* __restrict__ partC,
                                               float* __restrict__ part2F,
                                               float* __restrict__ part2C,
                                               int nfb, int chunks) {
  int t = threadIdx.x;
  int b = blockIdx.x;
  if (b < NG1F) {
    int per = (nfb + NG1F - 1) / NG1F;
    int r0 = b * per, r1 = min(r0 + per, nfb);
    float a0 = 0.f, a1 = 0.f, a2 = 0.f, a3 = 0.f;
    int r = r0;
    for (; r + 4 <= r1; r += 4) {
      float x0[4], x1[4], x2[4], x3[4];
#pragma unroll
      for (int j = 0; j < 4; ++j) {
        unsigned base = (unsigned)(r + j) * 771u;
        x0[j] = partF[base + t];
        x1[j] = partF[base + t + 256];
        x2[j] = (t + 512 < 771) ? partF[base + t + 512] : 0.f;
        x3[j] = (t < 3) ? partF[base + t + 768] : 0.f;
      }
#pragma unroll
      for (int j = 0; j < 4; ++j) {
        a0 += x0[j]; a1 += x1[j]; a2 += x2[j]; a3 += x3[j];
      }
    }
    for (; r < r1; ++r) {
      unsigned base = (unsigned)r * 771u;
      a0 += partF[base + t];
      a1 += partF[base + t + 256];
      if (t + 512 < 771) a2 += partF[base + t + 512];
      if (t < 3) a3 += partF[base + t + 768];
    }
    part2F[(unsigned)t * NG1F + b] = a0;
    part2F[(unsigned)(t + 256) * NG1F + b] = a1;
    if (t + 512 < 771) part2F[(unsigned)(t + 512) * NG1F + b] = a2;
    if (t < 3) part2F[(unsigned)(t + 768) * NG1F + b] = a3;
  } else {
    int rg = b - NG1F;
    int per = (chunks + NG1C - 1) / NG1C;
    int r0 = rg * per, r1 = min(r0 + per, chunks);
    float a0 = 0.f, a1 = 0.f;
    int r = r0;
    for (; r + 4 <= r1; r += 4) {
      float x0[4], x1[4];
#pragma unroll
      for (int j = 0; j < 4; ++j) {
        unsigned base = (unsigned)(r + j) * 257u;
        x0[j] = partC[base + t];
        x1[j] = (t == 0) ? partC[base + 256] : 0.f;
      }
#pragma unroll
      for (int j = 0; j < 4; ++j) { a0 += x0[j]; a1 += x1[j]; }
    }
    for (; r < r1; ++r) {
      unsigned base = (unsigned)r * 257u;
      a0 += partC[base + t];
      if (t == 0) a1 += partC[base + 256];
    }
    part2C[(unsigned)t * NG1C + rg] = a0;
    if (t == 0) part2C[256u * NG1C + rg] = a1;
  }
}

// ---------- norm stage 2: block per column, coalesced reads, LDS tree ----------
__global__ __launch_bounds__(256) void k_norm2(const float* __restrict__ part2F,
                                               const float* __restrict__ part2C,
                                               float* __restrict__ invn) {
  __shared__ float red[256];
  int c = blockIdx.x, t = threadIdx.x;
  float s;
  if (c >= 257 && c < 514) {
    int m = c - 257;
    s = (t < NG1C) ? part2C[(unsigned)m * NG1C + t] : 0.f;
  } else {
    int i = (c < 257) ? c : c - 257;
    s = part2F[(unsigned)i * NG1F + t] + part2F[(unsigned)i * NG1F + t + 256];
  }
  red[t] = s;
  __syncthreads();
  for (int o = 128; o > 0; o >>= 1) {
    if (t < o) red[t] += red[t + o];
    __syncthreads();
  }
  if (t == 0) invn[c] = 1.0f / fmaxf(sqrtf(red[0]), 1e-12f);
}

// ---------- scale pass: frame-major, no modulo, invn in registers ----------
__global__ __launch_bounds__(320) void k_scale(float4* __restrict__ out4,
                                               const float* __restrict__ invn,
                                               int nframes) {
  int t = threadIdx.x;
  if (t >= 257) return;
  float4 iv = make_float4(invn[4 * t], invn[4 * t + 1], invn[4 * t + 2], invn[4 * t + 3]);
  for (unsigned fr = blockIdx.x; fr < (unsigned)nframes; fr += gridDim.x) {
    unsigned idx = fr * 257u + t;
    float4 v = out4[idx];
    v.x *= iv.x;
    v.y *= iv.y;
    v.z *= iv.z;
    v.w *= iv.w;
    out4[idx] = v;
  }
}

extern "C" void kernel_launch(void* const* d_in, const int* in_sizes, int n_in,
                              void* d_out, int out_size, void* d_ws, size_t ws_size,
                              hipStream_t stream) {
  const float* audio = (const float*)d_in[0];
  const float* fb = (const float*)d_in[1];
  int T = in_sizes[0];
  int nframes = 1 + T / HOP;  // center=True, pad = NFFT/2 both sides
  float* out = (float*)d_out;
  int chunks = (nframes + CHUNK - 1) / CHUNK;
  int nfb = (nframes + 1) / 2;   // one FFT (2 frames) per block

  // ws layout (floats): twg[1024] | mend[chunks*257] | invn[1028] |
  //   lohi[514](int) | partC[chunks*257] | part2F[771*NG1F] | part2C[257*NG1C] |
  //   segB[nfb*257] | partF[nfb*771]
  float* wsf = (float*)d_ws;
  float2* twg = (float2*)wsf;
  float* mend = wsf + 1024;
  float* invn = mend + (long)chunks * NBINS;
  int* lohi = (int*)(invn + ROW);
  float* partC = (float*)(lohi + 2 * NBINS);
  float* part2F = partC + (long)chunks * NBINS;
  float* part2C = part2F + 771L * NG1F;
  float* segB = part2C + 257L * NG1C;
  float* partF = segB + (long)nfb * NBINS;

  k_prep<<<1, 256, 0, stream>>>(fb, lohi, twg);
  k_fft<<<nfb, 128, 0, stream>>>(audio, fb, lohi, twg, out, partF, segB, T, nframes);
  k_mend<<<chunks, 320, 0, stream>>>(segB, mend, nfb, chunks);
  k_pcen_c<<<chunks, 320, 0, stream>>>(out, mend, partC, nframes);
  k_norm1<<<NG1F + NG1C, 256, 0, stream>>>(partF, partC, part2F, part2C, nfb, chunks);
  k_norm2<<<ROW, 256, 0, stream>>>(part2F, part2C, invn);
  k_scale<<<2048, 320, 0, stream>>>((float4*)out, invn, nframes);
}

// Round 20
// 182.012 us; speedup vs baseline: 1.0558x; 1.0558x over previous
//
#include <hip/hip_runtime.h>
#include <math.h>

#define NFFT 512
#define HOP 128
#define NBINS 257
#define ROW 1028          // 4*257
#define CHUNK 64
#define LAM64 0.19783147f // 0.975^64
#define LAM4  0.90368789f // 0.975^4
#define NG1F 512
#define NG1C 128
// LDS swizzle for FFT buffers: bijective, applied to EVERY access.
#define SWZ(a) ((a) ^ (((a) >> 4) & 15))

__device__ __forceinline__ float2 cmul(float2 a, float2 b) {
  return make_float2(a.x * b.x - a.y * b.y, a.x * b.y + a.y * b.x);
}

struct EB { float lg, sv, cv, msp; };

// ---------- prep: twiddle table (once) + sparse filterbank spans ----------
__global__ void k_prep(const float* __restrict__ fb, int* __restrict__ lohi,
                       float2* __restrict__ twg) {
  int t = threadIdx.x;
  for (int i = t; i < NFFT; i += 256) {
    double ang = -6.283185307179586476925286766559 * (double)i / (double)NFFT;
    twg[i] = make_float2((float)cos(ang), (float)sin(ang));
  }
  for (int m = t; m < NBINS; m += 256) {
    int lo = 0, hi = -1;
    for (int f = 0; f < NBINS; ++f) {
      if (fb[f * NBINS + m] != 0.0f) { if (hi < 0) lo = f; hi = f; }
    }
    lohi[m] = lo;
    lohi[NBINS + m] = hi;
  }
}

// ---------- per-bin epilogue (S = swizzled LDS array, off = subarray base) ----------
__device__ __forceinline__ EB epilogue_bin(const float2* __restrict__ S, int off,
                                           float* __restrict__ out, unsigned ob,
                                           int k, bool store) {
  float2 z = S[SWZ(off + k)];
  float mag, sv, cv;
  if (k == 0 || k == 256) {
    // z.y is EXACTLY 0 here. The f32 reference's sin column at these bins is
    // either 0 (re>=0) or the single constant sin(pi_f32) (re<0). After
    // F.normalize the column becomes sign/sqrt(N_neg) — independent of the
    // constant's magnitude — so a cheap sign-select replaces sinf(atan2f()).
    mag = fabsf(z.x);
    sv = (z.x < 0.0f) ? -8.742278e-8f : 0.0f;
    cv = copysignf(1.0f, z.x);
  } else {
    float r2 = fmaf(z.x, z.x, z.y * z.y);
    if (r2 > 0.0f) {
      float rs = __builtin_amdgcn_rsqf(r2);
      mag = r2 * rs;            // sqrt(r2) to ~1ulp
      sv = z.y * rs;            // sin(angle) = im/|z|
      cv = z.x * rs;            // cos(angle) = re/|z|
    } else { mag = 0.0f; sv = 0.0f; cv = 1.0f; }
  }
  float lg = __logf(mag + 1e-9f);
  if (store) {
    out[ob + k] = lg;
    out[ob + 2 * NBINS + k] = sv;
    out[ob + 3 * NBINS + k] = cv;
  }
  // hann spectrum via 3-tap stencil; X[-1] = conj(X[1])
  float2 zm, zp;
  if (k == 0) { float2 s1 = S[SWZ(off + 1)]; zm = make_float2(s1.x, -s1.y); }
  else zm = S[SWZ(off + k - 1)];
  zp = S[SWZ(off + k + 1)];
  float hr = 0.5f * z.x - 0.25f * (zm.x + zp.x);
  float hi = 0.5f * z.y - 0.25f * (zm.y + zp.y);
  EB e; e.lg = lg; e.sv = sv; e.cv = cv; e.msp = hr * hr + hi * hi;
  return e;
}

// ---------- unpack one bin: fused final radix-2 + real/imag split ----------
__device__ __forceinline__ void unpack_bin(const float2* __restrict__ x,
                                           float2* __restrict__ y, int k) {
  float2 Zk, Zm;
  if (k <= 255) {
    float2 a0 = x[SWZ(k)], a1 = x[SWZ(k + 256)];
    Zk = make_float2(a0.x + a1.x, a0.y + a1.y);
  } else {
    float2 a0 = x[SWZ(k - 256)], a1 = x[SWZ(k)];
    Zk = make_float2(a0.x - a1.x, a0.y - a1.y);
  }
  int m2 = (NFFT - k) & (NFFT - 1);
  if (k == 0 || k == 256) {
    Zm = Zk;                       // structural: X1.im = X2.im = 0 exactly
  } else if (m2 >= 256) {          // k in 1..255
    float2 b0 = x[SWZ(m2 - 256)], b1 = x[SWZ(m2)];
    Zm = make_float2(b0.x - b1.x, b0.y - b1.y);
  } else {                         // k == 257 -> m2 = 255
    float2 b0 = x[SWZ(m2)], b1 = x[SWZ(m2 + 256)];
    Zm = make_float2(b0.x + b1.x, b0.y + b1.y);
  }
  y[SWZ(k)] = make_float2(0.5f * (Zk.x + Zm.x), 0.5f * (Zk.y - Zm.y));
  y[SWZ(258 + k)] = make_float2(0.5f * (Zk.y + Zm.y), 0.5f * (Zm.x - Zk.x));
}

// ---------- 4 frames per block: 2 complex FFTs, radix-4 (fused 2x radix-2) ----------
// (r19's 128-thread split regressed: +51MB writes, no occupancy gain. This is
// the r18 shape — best known.) Twiddles loaded per-stage from global; stage 0
// fused with the audio load. Emits partF (ch0/2/3 sumsq partials) AND segB
// (per-block pcen-scan contribution) so pcen_a's mel re-read is eliminated.
__global__ __launch_bounds__(256) void k_fft(
    const float* __restrict__ audio, const float* __restrict__ fb,
    const int* __restrict__ lohi, const float2* __restrict__ twg,
    float* __restrict__ out, float* __restrict__ partF,
    float* __restrict__ segB, int T, int nframes) {
  __shared__ float2 bufA[2][520];
  __shared__ float2 bufB[2][520];

  const int t = threadIdx.x;
  const int ff = t >> 7;       // which FFT (0/1)
  const int v = t & 127;       // butterfly index within FFT
  const int frb = blockIdx.x * 4;
  const int fr0 = frb + 2 * ff;
  const int fr1 = fr0 + 1;
  const bool h0 = fr0 < nframes;
  const bool h1 = fr1 < nframes;

  float2* __restrict__ xa = bufA[ff];
  float2* __restrict__ xb = bufB[ff];

  // fused load + stage 0: packed frame pair z = frame0 + i*frame1, reflect pad
  int s0 = fr0 * HOP - NFFT / 2;
  float2 xr[4];
#pragma unroll
  for (int j = 0; j < 4; ++j) {
    int i = v + 128 * j;
    int q0 = s0 + i;
    if (q0 < 0) q0 = -q0;
    if (q0 >= T) q0 = 2 * T - 2 - q0;
    int q1 = s0 + HOP + i;
    if (q1 < 0) q1 = -q1;
    if (q1 >= T) q1 = 2 * T - 2 - q1;
    xr[j] = make_float2(audio[q0], h1 ? audio[q1] : 0.0f);
  }
  {
    // stage 0 (m=1, qm=v, o=4v), register-local
    float2 w1 = twg[v], w2 = twg[2 * v], w3 = twg[3 * v];
    float2 s02 = make_float2(xr[0].x + xr[2].x, xr[0].y + xr[2].y);
    float2 d02 = make_float2(xr[0].x - xr[2].x, xr[0].y - xr[2].y);
    float2 s13 = make_float2(xr[1].x + xr[3].x, xr[1].y + xr[3].y);
    float2 d13 = make_float2(xr[1].x - xr[3].x, xr[1].y - xr[3].y);
    int o = 4 * v;
    xb[SWZ(o)] = make_float2(s02.x + s13.x, s02.y + s13.y);
    xb[SWZ(o + 1)] = cmul(w1, make_float2(d02.x + d13.y, d02.y - d13.x));  // d02 - i*d13
    xb[SWZ(o + 2)] = cmul(w2, make_float2(s02.x - s13.x, s02.y - s13.y));
    xb[SWZ(o + 3)] = cmul(w3, make_float2(d02.x - d13.y, d02.y + d13.x));  // d02 + i*d13
  }
  __syncthreads();

  // stages 1..3: xb -> xa -> xb -> xa (hoisted swizzled read addresses)
  const int ra0 = SWZ(v), ra1 = SWZ(v + 128), ra2 = SWZ(v + 256), ra3 = SWZ(v + 384);
  float2* x = xb;
  float2* y = xa;
#pragma unroll
  for (int ds = 1; ds < 4; ++ds) {
    const int m = 1 << (2 * ds);
    int qm = v & ~(m - 1);
    int r = v - qm;
    int o = 4 * qm + r;
    float2 w1 = twg[qm];
    float2 w2 = twg[2 * qm];
    float2 w3 = twg[3 * qm];
    float2 x0 = x[ra0], x1 = x[ra1], x2 = x[ra2], x3 = x[ra3];
    float2 s02 = make_float2(x0.x + x2.x, x0.y + x2.y);
    float2 d02 = make_float2(x0.x - x2.x, x0.y - x2.y);
    float2 s13 = make_float2(x1.x + x3.x, x1.y + x3.y);
    float2 d13 = make_float2(x1.x - x3.x, x1.y - x3.y);
    float2 E0 = make_float2(s02.x + s13.x, s02.y + s13.y);
    float2 u1 = make_float2(d02.x + d13.y, d02.y - d13.x);  // d02 - i*d13
    float2 u2 = make_float2(s02.x - s13.x, s02.y - s13.y);
    float2 u3 = make_float2(d02.x - d13.y, d02.y + d13.x);  // d02 + i*d13
    float2 E1 = cmul(w1, u1);
    float2 E2 = cmul(w2, u2);
    float2 E3 = cmul(w3, u3);
    y[SWZ(o)] = E0;
    y[SWZ(o + m)] = E1;
    y[SWZ(o + 2 * m)] = E2;
    y[SWZ(o + 3 * m)] = E3;
    __syncthreads();
    float2* tmp = x; x = y; y = tmp;
  }
  // After the loop: x == bufA[ff] (stage-3 output), y == bufB[ff].
  // Unpack: bins 0..255 in 2 full iterations; 256/257 by lanes v<2.
  unpack_bin(x, y, v);
  unpack_bin(x, y, v + 128);
  if (v < 2) unpack_bin(x, y, 256 + v);
  __syncthreads();

  // epilogue: bins 0..255 in 2 full iterations; bin 256 by lane v==0
  unsigned ob0 = (unsigned)fr0 * ROW;
  unsigned ob1 = (unsigned)fr1 * ROW;
  float mspA[2], mspB[2], sql[2], sqs[2], sqc[2];
#pragma unroll
  for (int ki = 0; ki < 2; ++ki) {
    int k = v + 128 * ki;
    EB e0 = epilogue_bin(y, 0, out, ob0, k, h0);
    EB e1 = epilogue_bin(y, 258, out, ob1, k, h1);
    mspA[ki] = e0.msp;
    mspB[ki] = e1.msp;
    sql[ki] = (h0 ? e0.lg * e0.lg : 0.f) + (h1 ? e1.lg * e1.lg : 0.f);
    sqs[ki] = (h0 ? e0.sv * e0.sv : 0.f) + (h1 ? e1.sv * e1.sv : 0.f);
    sqc[ki] = (h0 ? e0.cv * e0.cv : 0.f) + (h1 ? e1.cv * e1.cv : 0.f);
  }
  float mspA6 = 0.f, mspB6 = 0.f, sql6 = 0.f, sqs6 = 0.f, sqc6 = 0.f;
  if (v == 0) {
    EB e0 = epilogue_bin(y, 0, out, ob0, 256, h0);
    EB e1 = epilogue_bin(y, 258, out, ob1, 256, h1);
    mspA6 = e0.msp;
    mspB6 = e1.msp;
    sql6 = (h0 ? e0.lg * e0.lg : 0.f) + (h1 ? e1.lg * e1.lg : 0.f);
    sqs6 = (h0 ? e0.sv * e0.sv : 0.f) + (h1 ? e1.sv * e1.sv : 0.f);
    sqc6 = (h0 ? e0.cv * e0.cv : 0.f) + (h1 ? e1.cv * e1.cv : 0.f);
  }
  __syncthreads();   // all reads of y (spectra) done -> bufB reusable

  // park: mspec (both frames) in bufB[ff]; squares (sqf) in bufA[ff]
  float* mspSh = (float*)&bufB[ff][0];  // [0..257) frame0, [258..515) frame1; [520..777) seg
  float* sqf = (float*)&bufA[ff][0];    // ch0 [0..257), ch2 [258..515), ch3 [516..773)
#pragma unroll
  for (int ki = 0; ki < 2; ++ki) {
    int k = v + 128 * ki;
    mspSh[k] = mspA[ki];
    mspSh[258 + k] = mspB[ki];
    sqf[k] = sql[ki];
    sqf[258 + k] = sqs[ki];
    sqf[516 + k] = sqc[ki];
  }
  if (v == 0) {
    mspSh[256] = mspA6;
    mspSh[258 + 256] = mspB6;
    sqf[256] = sql6;
    sqf[258 + 256] = sqs6;
    sqf[516 + 256] = sqc6;
  }
  __syncthreads();

  // sparse mel for both frames; also write the per-frame-pair pcen partial
  // p = lam*a0 + a1 into bufB's free tail [520..777) (disjoint from the
  // [0..515] reads in this loop -> no extra barrier needed before it).
  for (int m = v; m < NBINS; m += 128) {
    int lo = lohi[m], hi = lohi[NBINS + m];
    float a0 = 0.0f, a1 = 0.0f;
    for (int f = lo; f <= hi; ++f) {
      float w = fb[f * NBINS + m];
      a0 = fmaf(mspSh[f], w, a0);
      a1 = fmaf(mspSh[258 + f], w, a1);
    }
    if (h0) out[ob0 + NBINS + m] = a0;
    if (h1) out[ob1 + NBINS + m] = a1;
    mspSh[520 + m] = fmaf(0.975f, a0, a1);   // lam*x_first + x_second
  }
  __syncthreads();

  // combine squares -> partF row (gaps at 257/515 skipped via lidx), and
  // seg = s*(lam^2 * p_ff0 + p_ff1)  [= s*(l^3 x0 + l^2 x1 + l x2 + x3)]
  const float* sq0 = (const float*)&bufA[0][0];
  const float* sq1 = (const float*)&bufA[1][0];
  const float* pg0 = (const float*)&bufB[0][0];
  const float* pg1 = (const float*)&bufB[1][0];
  for (int i = t; i < 771; i += 256) {
    int lidx = i + (i >= 257) + (i >= 514);
    partF[(unsigned)blockIdx.x * 771u + i] = sq0[lidx] + sq1[lidx];
  }
  for (int i = t; i < NBINS; i += 256) {
    segB[(unsigned)blockIdx.x * 257u + i] =
        0.025f * fmaf(0.950625f, pg0[520 + i], pg1[520 + i]);
  }
}

// ---------- mend from segs: mend[c] = sum_g LAM4^(15-g) seg[16c+g] ----------
__global__ __launch_bounds__(320) void k_mend(const float* __restrict__ segB,
                                              float* __restrict__ mend,
                                              int nfb, int chunks) {
  int m = threadIdx.x;
  if (m >= NBINS) return;
  int c = blockIdx.x;
  float xs[16];
#pragma unroll
  for (int g = 0; g < 16; ++g) {
    int b = 16 * c + g;
    xs[g] = (b < nfb) ? segB[(unsigned)b * 257u + m] : 0.0f;
  }
  float mm = 0.0f;
#pragma unroll
  for (int g = 0; g < 16; ++g) mm = fmaf(LAM4, mm, xs[g]);
  mend[c * NBINS + m] = mm;
}

// ---------- pcen phase C: init from prev 12 chunks' mend (LAM64^12=3.6e-9),
// scan+rewrite ch1; ch1 column-square partials free from registers ----------
__global__ __launch_bounds__(320) void k_pcen_c(float* __restrict__ out,
                                                const float* __restrict__ mend,
                                                float* __restrict__ partC,
                                                int nframes) {
  int m = threadIdx.x;
  if (m >= NBINS) return;
  int c = blockIdx.x;
  int F0 = c * CHUNK;
  int end = min(F0 + CHUNK, nframes);
  const float SS = 0.025f, OMS = 1.0f - SS;
  const float SQ2 = sqrtf(2.0f);
  float mm;
  if (c >= 12) {
    float xs[12];
#pragma unroll
    for (int j = 0; j < 12; ++j) xs[j] = mend[(c - 12 + j) * NBINS + m];
    mm = 0.0f;
#pragma unroll
    for (int j = 0; j < 12; ++j) mm = xs[j] + LAM64 * mm;
  } else {
    mm = 0.0f;
    for (int j = 0; j < c; ++j) mm = mend[j * NBINS + m] + LAM64 * mm;
  }
  float acc1 = 0.0f;
  int tf = F0;
  for (; tf + 16 <= end; tf += 16) {
    float xs[16], ys[16];
#pragma unroll
    for (int j = 0; j < 16; ++j) xs[j] = out[(unsigned)(tf + j) * ROW + NBINS + m];
#pragma unroll
    for (int j = 0; j < 16; ++j) {
      mm = OMS * mm + SS * xs[j];
      float invden = __expf(-0.98f * __logf(mm + 1e-6f));  // 1/den, no division
      float val = fmaf(xs[j], invden, 2.0f);
      float rs = __builtin_amdgcn_rsqf(val);
      ys[j] = val * rs - SQ2;   // sqrt(val) - sqrt(2), ~1ulp
      acc1 = fmaf(ys[j], ys[j], acc1);
    }
#pragma unroll
    for (int j = 0; j < 16; ++j) out[(unsigned)(tf + j) * ROW + NBINS + m] = ys[j];
  }
  for (; tf < end; ++tf) {
    unsigned idx = (unsigned)tf * ROW + NBINS + m;
    float xv = out[idx];
    mm = OMS * mm + SS * xv;
    float invden = __expf(-0.98f * __logf(mm + 1e-6f));
    float val = fmaf(xv, invden, 2.0f);
    float rs = __builtin_amdgcn_rsqf(val);
    float yv = val * rs - SQ2;
    acc1 = fmaf(yv, yv, acc1);
    out[idx] = yv;
  }
  partC[c * NBINS + m] = acc1;
}

// ---------- norm stage 1: coalesced AND parallel (512+128 blocks, 4-row batch) ----------
__global__ __launch_bounds__(256) void k_norm1(const float* __restrict__ partF,
                                               const float* __restrict__ partC,
                                               float* __restrict__ part2F,
                                               float* __restrict__ part2C,
                                               int nfb, int chunks) {
  int t = threadIdx.x;
  int b = blockIdx.x;
  if (b < NG1F) {
    int per = (nfb + NG1F - 1) / NG1F;
    int r0 = b * per, r1 = min(r0 + per, nfb);
    float a0 = 0.f, a1 = 0.f, a2 = 0.f, a3 = 0.f;
    int r = r0;
    for (; r + 4 <= r1; r += 4) {
      float x0[4], x1[4], x2[4], x3[4];
#pragma unroll
      for (int j = 0; j < 4; ++j) {
        unsigned base = (unsigned)(r + j) * 771u;
        x0[j] = partF[base + t];
        x1[j] = partF[base + t + 256];
        x2[j] = (t + 512 < 771) ? partF[base + t + 512] : 0.f;
        x3[j] = (t < 3) ? partF[base + t + 768] : 0.f;
      }
#pragma unroll
      for (int j = 0; j < 4; ++j) {
        a0 += x0[j]; a1 += x1[j]; a2 += x2[j]; a3 += x3[j];
      }
    }
    for (; r < r1; ++r) {
      unsigned base = (unsigned)r * 771u;
      a0 += partF[base + t];
      a1 += partF[base + t + 256];
      if (t + 512 < 771) a2 += partF[base + t + 512];
      if (t < 3) a3 += partF[base + t + 768];
    }
    part2F[(unsigned)t * NG1F + b] = a0;
    part2F[(unsigned)(t + 256) * NG1F + b] = a1;
    if (t + 512 < 771) part2F[(unsigned)(t + 512) * NG1F + b] = a2;
    if (t < 3) part2F[(unsigned)(t + 768) * NG1F + b] = a3;
  } else {
    int rg = b - NG1F;
    int per = (chunks + NG1C - 1) / NG1C;
    int r0 = rg * per, r1 = min(r0 + per, chunks);
    float a0 = 0.f, a1 = 0.f;
    int r = r0;
    for (; r + 4 <= r1; r += 4) {
      float x0[4], x1[4];
#pragma unroll
      for (int j = 0; j < 4; ++j) {
        unsigned base = (unsigned)(r + j) * 257u;
        x0[j] = partC[base + t];
        x1[j] = (t == 0) ? partC[base + 256] : 0.f;
      }
#pragma unroll
      for (int j = 0; j < 4; ++j) { a0 += x0[j]; a1 += x1[j]; }
    }
    for (; r < r1; ++r) {
      unsigned base = (unsigned)r * 257u;
      a0 += partC[base + t];
      if (t == 0) a1 += partC[base + 256];
    }
    part2C[(unsigned)t * NG1C + rg] = a0;
    if (t == 0) part2C[256u * NG1C + rg] = a1;
  }
}

// ---------- norm stage 2: block per column, coalesced reads, LDS tree ----------
__global__ __launch_bounds__(256) void k_norm2(const float* __restrict__ part2F,
                                               const float* __restrict__ part2C,
                                               float* __restrict__ invn) {
  __shared__ float red[256];
  int c = blockIdx.x, t = threadIdx.x;
  float s;
  if (c >= 257 && c < 514) {
    int m = c - 257;
    s = (t < NG1C) ? part2C[(unsigned)m * NG1C + t] : 0.f;
  } else {
    int i = (c < 257) ? c : c - 257;
    s = part2F[(unsigned)i * NG1F + t] + part2F[(unsigned)i * NG1F + t + 256];
  }
  red[t] = s;
  __syncthreads();
  for (int o = 128; o > 0; o >>= 1) {
    if (t < o) red[t] += red[t + o];
    __syncthreads();
  }
  if (t == 0) invn[c] = 1.0f / fmaxf(sqrtf(red[0]), 1e-12f);
}

// ---------- scale pass: frame-major, no modulo, invn in registers ----------
__global__ __launch_bounds__(320) void k_scale(float4* __restrict__ out4,
                                               const float* __restrict__ invn,
                                               int nframes) {
  int t = threadIdx.x;
  if (t >= 257) return;
  float4 iv = make_float4(invn[4 * t], invn[4 * t + 1], invn[4 * t + 2], invn[4 * t + 3]);
  for (unsigned fr = blockIdx.x; fr < (unsigned)nframes; fr += gridDim.x) {
    unsigned idx = fr * 257u + t;
    float4 v = out4[idx];
    v.x *= iv.x;
    v.y *= iv.y;
    v.z *= iv.z;
    v.w *= iv.w;
    out4[idx] = v;
  }
}

extern "C" void kernel_launch(void* const* d_in, const int* in_sizes, int n_in,
                              void* d_out, int out_size, void* d_ws, size_t ws_size,
                              hipStream_t stream) {
  const float* audio = (const float*)d_in[0];
  const float* fb = (const float*)d_in[1];
  int T = in_sizes[0];
  int nframes = 1 + T / HOP;  // center=True, pad = NFFT/2 both sides
  float* out = (float*)d_out;
  int chunks = (nframes + CHUNK - 1) / CHUNK;
  int nfb = (nframes + 3) / 4;

  // ws layout (floats): twg[1024] | mend[chunks*257] | invn[1028] |
  //   lohi[514](int) | partC[chunks*257] | part2F[771*NG1F] | part2C[257*NG1C] |
  //   segB[nfb*257] | partF[nfb*771]
  float* wsf = (float*)d_ws;
  float2* twg = (float2*)wsf;
  float* mend = wsf + 1024;
  float* invn = mend + (long)chunks * NBINS;
  int* lohi = (int*)(invn + ROW);
  float* partC = (float*)(lohi + 2 * NBINS);
  float* part2F = partC + (long)chunks * NBINS;
  float* part2C = part2F + 771L * NG1F;
  float* segB = part2C + 257L * NG1C;
  float* partF = segB + (long)nfb * NBINS;

  k_prep<<<1, 256, 0, stream>>>(fb, lohi, twg);
  k_fft<<<nfb, 256, 0, stream>>>(audio, fb, lohi, twg, out, partF, segB, T, nframes);
  k_mend<<<chunks, 320, 0, stream>>>(segB, mend, nfb, chunks);
  k_pcen_c<<<chunks, 320, 0, stream>>>(out, mend, partC, nframes);
  k_norm1<<<NG1F + NG1C, 256, 0, stream>>>(partF, partC, part2F, part2C, nfb, chunks);
  k_norm2<<<ROW, 256, 0, stream>>>(part2F, part2C, invn);
  k_scale<<<2048, 320, 0, stream>>>((float4*)out, invn, nframes);
}